// Round 1
// baseline (4399.063 us; speedup 1.0000x reference)
//
#include <hip/hip_runtime.h>
#include <stdint.h>

// Problem constants (from reference)
#define NN      5000
#define NE      4000
#define NB      8
#define TSTEPS  256
#define NDELAY  15
#define WPR     160          // uint32 words per mask row (157 used, padded to 160)
#define IPB     256          // threads (i's) per block
#define BPB     20           // blocks per batch = ceil(5000/256)
#define NBLK    (NB*BPB)     // 160 blocks -> co-resident on 256 CUs
#define LIST_SLOTS 32        // ring depth for spike index lists (> 2*NDELAY)

// Workspace layout (bytes)
#define MASK_BYTES (NN*WPR*4)              // 3,200,000
#define CNT_OFF    MASK_BYTES
#define CNT_BYTES  (TSTEPS*NB*4)           // 8,192
#define BAR_OFF    (CNT_OFF + CNT_BYTES)
#define BAR_BYTES  128
#define LIST_OFF   (BAR_OFF + BAR_BYTES)
#define LIST_BYTES (LIST_SLOTS*NB*NN*4)    // 5,120,000
#define ZERO_BYTES LIST_OFF                // zero mask + counts + barrier each launch

// ---------------------------------------------------------------------------
// Kernel 1: transpose + bit-pack connectivity. maskbits[j][i>>5] bit (i&31)
// set iff W[i,j] != 0.  W is [N,N] row-major, reads fully coalesced.
// ---------------------------------------------------------------------------
__global__ void _Brunel_build_mask(const float* __restrict__ W,
                                   uint32_t* __restrict__ maskbits)
{
    int j = blockIdx.x * blockDim.x + threadIdx.x;   // presyn (column of W)
    int i = blockIdx.y;                              // postsyn (row of W)
    if (j >= NN) return;
    float w = W[(size_t)i * NN + j];
    if (w != 0.0f)
        atomicOr(&maskbits[(size_t)j * WPR + (i >> 5)], 1u << (i & 31));
}

// ---------------------------------------------------------------------------
// Kernel 2: persistent SNN simulation.
//  - block bb owns batch b = bb/BPB and 256 consecutive neurons i.
//  - v lives in a register for all 256 steps.
//  - recurrent input: iterate compact spike list of (t-15, b), count connected
//    exc/inh presyn via the bitmask (exact integers).
//  - spike lists appended with ballot-compaction + 1 atomicAdd per wave.
//  - grid barrier (monotonic counter) only every NDELAY steps.
// ---------------------------------------------------------------------------
__global__ void __launch_bounds__(IPB, 1) _Brunel_persist(
    const float* __restrict__ ext,
    const uint32_t* __restrict__ maskbits,
    int* __restrict__ counts,
    int* __restrict__ lists,
    int* __restrict__ bar,
    float* __restrict__ out_spk,
    float* __restrict__ out_vs)
{
    const int bb  = blockIdx.x;
    const int b   = bb / BPB;
    const int i   = (bb % BPB) * IPB + threadIdx.x;
    const bool act = (i < NN);
    const int lane = threadIdx.x & 63;

    float v = 0.0f;
    int bcount = 0;                 // barrier generation (thread 0 only uses it)

    __shared__ int s_cnt;
    __shared__ int s_list[NN];      // 20 KB LDS

    for (int t = 0; t < TSTEPS; ++t) {
        // ---- fetch spike list of step t-NDELAY (zeros for t < NDELAY) ----
        int cnt = 0;
        if (t >= NDELAY) {
            const int ts = t - NDELAY;
            if (threadIdx.x == 0) s_cnt = counts[ts * NB + b];
            __syncthreads();
            cnt = s_cnt;
            const int* src = lists + ((size_t)(ts & (LIST_SLOTS - 1)) * NB + b) * NN;
            for (int k = threadIdx.x; k < cnt; k += IPB) s_list[k] = src[k];
        }
        __syncthreads();

        // ---- neuron update ----
        float sflag = 0.0f;
        if (act) {
            int cE = 0, cI = 0;
            const int wofs = i >> 5;
            const int sh   = i & 31;
            const uint32_t* __restrict__ mb = maskbits + wofs;
#pragma unroll 4
            for (int k = 0; k < cnt; ++k) {
                int j = s_list[k];                       // LDS broadcast
                uint32_t w = mb[(size_t)j * WPR];        // L2-resident gather
                int bit = (int)((w >> sh) & 1u);
                if (j < NE) cE += bit; else cI += bit;   // j uniform per wave
            }
            float cur  = 0.1f * (float)cE - 0.5f * (float)cI;
            float x    = ext[((size_t)t * NB + b) * NN + i];
            float itot = cur + x;                        // match ref association
            v = v * 0.95f + itot;
            bool s = (v >= 1.0f);
            sflag = s ? 1.0f : 0.0f;
            float vout = s ? 0.0f : v;
            size_t o = ((size_t)t * NB + b) * NN + i;
            out_spk[o] = sflag;
            out_vs[o]  = vout;
            v = vout;
        }

        // ---- append spiking indices to list slot t&31 (ballot compaction) --
        {
            unsigned long long m = __ballot(sflag != 0.0f);
            if (m) {
                int leader = __ffsll((unsigned long long)m) - 1;
                int nsp    = __popcll(m);
                int base   = 0;
                if (lane == leader) base = atomicAdd(&counts[t * NB + b], nsp);
                base = __shfl(base, leader, 64);
                if (sflag != 0.0f) {
                    int pos = __popcll(m & ((1ull << lane) - 1ull));
                    lists[((size_t)(t & (LIST_SLOTS - 1)) * NB + b) * NN + base + pos] = i;
                }
            }
        }
        __syncthreads();   // protect s_list before next iteration's overwrite

        // ---- grid barrier every NDELAY steps (delay gives the slack) ------
        if (t % NDELAY == NDELAY - 1) {
            if (threadIdx.x == 0) {
                __threadfence();                       // release (L2 wb)
                atomicAdd(bar, 1);
                ++bcount;
                const int target = bcount * NBLK;      // monotonic counter
                while (atomicAdd(bar, 0) < target) {
                    __builtin_amdgcn_s_sleep(8);
                }
                __threadfence();                       // acquire (L1/L2 inv)
            }
            __syncthreads();
        }
    }
}

// ---------------------------------------------------------------------------
extern "C" void kernel_launch(void* const* d_in, const int* in_sizes, int n_in,
                              void* d_out, int out_size, void* d_ws, size_t ws_size,
                              hipStream_t stream)
{
    const float* ext = (const float*)d_in[0];   // [T,B,N] fp32
    const float* W   = (const float*)d_in[1];   // [N,N]   fp32

    float* out_spk = (float*)d_out;                          // [T,B,N]
    float* out_vs  = out_spk + (size_t)TSTEPS * NB * NN;     // [T,B,N]

    uint8_t* ws      = (uint8_t*)d_ws;
    uint32_t* mask   = (uint32_t*)(ws);
    int*      counts = (int*)(ws + CNT_OFF);
    int*      bar    = (int*)(ws + BAR_OFF);
    int*      lists  = (int*)(ws + LIST_OFF);

    // zero mask + counts + barrier (deterministic per call; lists gated by counts)
    hipMemsetAsync(ws, 0, ZERO_BYTES, stream);

    dim3 gmask(BPB, NN);   // (20, 5000), 256 thr: coalesced over j
    _Brunel_build_mask<<<gmask, IPB, 0, stream>>>(W, mask);

    _Brunel_persist<<<NBLK, IPB, 0, stream>>>(ext, mask, counts, lists, bar,
                                              out_spk, out_vs);
}

// Round 2
// 731.866 us; speedup vs baseline: 6.0108x; 6.0108x over previous
//
#include <hip/hip_runtime.h>
#include <stdint.h>

// Problem constants (from reference)
#define NN      5000
#define NE      4000
#define NB      8
#define TSTEPS  256
#define NDELAY  15
#define NW      157          // uint32 words covering 5000 presyn bits
#define NWE     125          // exc words: j in [0,4000), 4000/32 = 125 exactly
#define NWI     32           // inh words: 125..156 (bits >= 5000 always zero)
#define NIPAD   5120         // padded neuron dim (columns of maskT2)
#define RW      160          // ring row stride in words
#define IPB     256          // threads per block
#define BPB     20           // blocks per batch
#define NBLK    (NB*BPB)     // 160 blocks -> 1 per CU, co-resident
#define RING_SLOTS 32        // step distance writer->reader is 15..29 < 32

// Workspace layout (bytes)
#define MASK_BYTES (RW*NIPAD*4)          // 3,276,800 (rows 0..156 used, pad cols zeroed)
#define BAR_OFF    MASK_BYTES
#define BAR_BYTES  128
#define RING_OFF   (BAR_OFF + BAR_BYTES)
#define RING_BYTES (RING_SLOTS*NB*RW*4)  // 163,840
#define ZERO_BYTES (MASK_BYTES + BAR_BYTES)   // zero mask (pad cols!) + barrier

// ---------------------------------------------------------------------------
// Kernel 1: bit-pack connectivity, word-major-transposed:
//   maskT2[w*NIPAD + i] bit (j&31), w=j>>5, set iff W[i,j] != 0.
// Reads of W fully coalesced; writes 2 words per wave via ballot (no atomics).
// ---------------------------------------------------------------------------
__global__ void _Brunel_build_mask(const float* __restrict__ W,
                                   uint32_t* __restrict__ maskT2)
{
    int j = blockIdx.x * blockDim.x + threadIdx.x;   // presyn 0..5119
    int i = blockIdx.y;                              // postsyn row 0..4999
    int lane = threadIdx.x & 63;
    bool nz = false;
    if (j < NN) nz = (W[(size_t)i * NN + j] != 0.0f);
    unsigned long long m = __ballot(nz);
    if ((lane & 31) == 0 && j < NN) {
        uint32_t wd = (lane == 0) ? (uint32_t)m : (uint32_t)(m >> 32);
        maskT2[(size_t)(j >> 5) * NIPAD + i] = wd;
    }
}

// ---------------------------------------------------------------------------
// Kernel 2: persistent SNN sim. Mask row lives in ~157 VGPRs for all 256
// steps. Per step: stage 157 wave-uniform spike words into LDS, then
// cE/cI = sum of popc(spike & mask) -- fixed work, zero gathers.
// Spike words produced by ballot, written straight to a global ring
// (no atomics, no lists). Grid barrier every NDELAY steps.
// ---------------------------------------------------------------------------
__global__ void __launch_bounds__(IPB, 1) _Brunel_persist(
    const float* __restrict__ ext,
    const uint32_t* __restrict__ maskT2,
    uint32_t* __restrict__ ring,
    int* __restrict__ bar,
    float* __restrict__ out_spk,
    float* __restrict__ out_vs)
{
    const int tx   = threadIdx.x;
    const int bb   = blockIdx.x;
    const int b    = bb / BPB;
    const int i    = (bb % BPB) * IPB + tx;
    const bool act = (i < NN);
    const int lane = tx & 63;

    // ---- connectivity row -> registers (pad columns are memset-zero) ----
    uint32_t mreg[160];
#pragma unroll
    for (int w = 0; w < NW; ++w) mreg[w] = maskT2[(size_t)w * NIPAD + i];
#pragma unroll
    for (int w = NW; w < 160; ++w) mreg[w] = 0u;

    __shared__ __align__(16) uint32_t s_exc[128];   // words 0..124 (+3 zero pad)
    __shared__ __align__(16) uint32_t s_inh[32];    // words 125..156

    if (tx >= NWE && tx < 128) s_exc[tx] = 0u;      // persistent zero pad
    __syncthreads();

    float v = 0.0f;
    int bcnt = 0;

    for (int t = 0; t < TSTEPS; ++t) {
        // issue external-input load early (used ~800 cyc later)
        float x = 0.0f;
        if (act) x = ext[((size_t)t * NB + b) * NN + i];

        // ---- stage delayed spike words (t-NDELAY) into LDS ----
        if (t >= NDELAY) {
            const int slot = (t - NDELAY) & (RING_SLOTS - 1);
            const uint32_t* src = ring + ((size_t)slot * NB + b) * RW;
            if (tx < NW) {
                uint32_t wd = src[tx];
                if (tx < NWE) s_exc[tx] = wd; else s_inh[tx - NWE] = wd;
            }
        }
        __syncthreads();

        // ---- exact integer synapse counts via AND+POPC ----
        int e0 = 0, e1 = 0, e2 = 0, e3 = 0;
        int c0 = 0, c1 = 0, c2 = 0, c3 = 0;
        if (t >= NDELAY) {
            const uint4* se = (const uint4*)s_exc;
            const uint4* si = (const uint4*)s_inh;
#pragma unroll
            for (int c = 0; c < 32; ++c) {
                uint4 sw = se[c];
                e0 = __popc(sw.x & mreg[4 * c + 0]) + e0;
                e1 = __popc(sw.y & mreg[4 * c + 1]) + e1;
                e2 = __popc(sw.z & mreg[4 * c + 2]) + e2;
                e3 = __popc(sw.w & mreg[4 * c + 3]) + e3;
            }
#pragma unroll
            for (int c = 0; c < 8; ++c) {
                uint4 sw = si[c];
                c0 = __popc(sw.x & mreg[NWE + 4 * c + 0]) + c0;
                c1 = __popc(sw.y & mreg[NWE + 4 * c + 1]) + c1;
                c2 = __popc(sw.z & mreg[NWE + 4 * c + 2]) + c2;
                c3 = __popc(sw.w & mreg[NWE + 4 * c + 3]) + c3;
            }
        }
        int cE = (e0 + e1) + (e2 + e3);
        int cI = (c0 + c1) + (c2 + c3);

        // ---- neuron update (matches reference association exactly) ----
        float cur  = 0.1f * (float)cE - 0.5f * (float)cI;
        float itot = cur + x;
        v = v * 0.95f + itot;
        bool s = act && (v >= 1.0f);
        float sflag = s ? 1.0f : 0.0f;
        float vout  = s ? 0.0f : v;
        if (act) {
            size_t o = ((size_t)t * NB + b) * NN + i;
            out_spk[o] = sflag;
            out_vs[o]  = vout;
        }
        v = vout;

        // ---- pack this step's spikes into the ring (2 words per wave) ----
        {
            unsigned long long m = __ballot(s);
            if ((lane & 31) == 0 && act) {
                uint32_t wd = (lane == 0) ? (uint32_t)m : (uint32_t)(m >> 32);
                ring[((size_t)(t & (RING_SLOTS - 1)) * NB + b) * RW + (i >> 5)] = wd;
            }
        }

        // ---- sync: LDS reuse each step; grid barrier every NDELAY steps ----
        if ((t % NDELAY) == (NDELAY - 1)) {
            __threadfence();          // every wave drains its own stores (release)
            __syncthreads();
            if (tx == 0) {
                atomicAdd(bar, 1);
                ++bcnt;
                const int target = bcnt * NBLK;
                while (atomicAdd(bar, 0) < target) __builtin_amdgcn_s_sleep(8);
                __threadfence();      // acquire: invalidate L1/L2 for ring reads
            }
            __syncthreads();
        } else {
            __syncthreads();          // protect s_exc/s_inh before next staging
        }
    }
}

// ---------------------------------------------------------------------------
extern "C" void kernel_launch(void* const* d_in, const int* in_sizes, int n_in,
                              void* d_out, int out_size, void* d_ws, size_t ws_size,
                              hipStream_t stream)
{
    const float* ext = (const float*)d_in[0];   // [T,B,N] fp32
    const float* W   = (const float*)d_in[1];   // [N,N]   fp32

    float* out_spk = (float*)d_out;                          // [T,B,N]
    float* out_vs  = out_spk + (size_t)TSTEPS * NB * NN;     // [T,B,N]

    uint8_t*  ws     = (uint8_t*)d_ws;
    uint32_t* mask   = (uint32_t*)(ws);
    int*      bar    = (int*)(ws + BAR_OFF);
    uint32_t* ring   = (uint32_t*)(ws + RING_OFF);

    // zero mask (pad columns must read 0) + barrier counter
    hipMemsetAsync(ws, 0, ZERO_BYTES, stream);

    dim3 gmask(NIPAD / IPB, NN);   // (20, 5000)
    _Brunel_build_mask<<<gmask, IPB, 0, stream>>>(W, mask);

    _Brunel_persist<<<NBLK, IPB, 0, stream>>>(ext, mask, ring, bar,
                                              out_spk, out_vs);
}